// Round 19
// baseline (133.514 us; speedup 1.0000x reference)
//
#include <hip/hip_runtime.h>

// ---------------- problem constants ----------------
#define DM    1024          // d_model
#define NEXP  8             // experts
#define BTOK  8192          // tokens
#define KTOP  2             // routes per token
#define NASSIGN (BTOK*KTOP) // 16384
#define CAPC  1280          // capacity (5 * 256 -> tile-aligned)
#define MROWS (NEXP*CAPC)   // 10240 expert rows

// GEMM geometry: 256M x 128N tile, BK=32, 8 waves (4Mx2N), per-wave 64x64
#define NTILES   (DM/128)      // 8
#define SLOTS_E  (5*NTILES)    // 40 expert slots per XCD (5 Mtiles x 8 N)
#define SLOTS_F  (32*NTILES/8) // 32 fb slots per XCD
#define SLOTS    (SLOTS_E+SLOTS_F)    // 72
#define GRID_L   (8*SLOTS)            // 576

typedef unsigned short ushort_t;
typedef __attribute__((ext_vector_type(8))) __bf16 bf16x8;
typedef __attribute__((ext_vector_type(4))) float  f32x4;

__device__ __forceinline__ ushort_t f2b(float f) {  // f32 -> bf16 RNE
  union { float f; unsigned u; } a; a.f = f;
  unsigned u = a.u;
  return (ushort_t)((u + 0x7FFFu + ((u >> 16) & 1u)) >> 16);
}
__device__ __forceinline__ float b2f(ushort_t h) {
  union { unsigned u; float f; } a; a.u = ((unsigned)h) << 16;
  return a.f;
}

#define GLOAD_LDS(g, l) __builtin_amdgcn_global_load_lds( \
    (const __attribute__((address_space(1))) void*)(g),   \
    (__attribute__((address_space(3))) void*)(l), 16, 0, 0)

// ---------------- merged: routing (blocks 0..7) + W1/Wf1 cvt (blocks 8..) ----
// r19: W2/Wf2 cvt moved to gather_xf's grid (not needed until layer 2) so it
// overlaps the pre-layer-1 latency window instead of running serially here.
__global__ void route_cvt_kernel(const int* __restrict__ routes, const int* __restrict__ capp,
                                 int* __restrict__ gidx, int* __restrict__ slot,
                                 int* __restrict__ counts, int* __restrict__ nfb,
                                 const float* __restrict__ W1, const float* __restrict__ Wf1,
                                 ushort_t* __restrict__ o1, ushort_t* __restrict__ of1) {
  const int b = blockIdx.x, t = threadIdx.x;
  if (b >= 8) {                          // weight f32 -> bf16 (layer-1 weights)
    const float* s; ushort_t* d; int idx;
    int c = b - 8;
    if (c < 2048) { s = W1;  d = o1;  idx = c; }
    else          { s = Wf1; d = of1; idx = c - 2048; }
    int i = idx * 1024 + t;
    float4 v = ((const float4*)s)[i];
    ushort4 o; o.x = f2b(v.x); o.y = f2b(v.y); o.z = f2b(v.z); o.w = f2b(v.w);
    ((ushort4*)d)[i] = o;
    return;
  }
  // ---- routing: exact sequential capacity semantics (block e = expert) ----
  const int e = b;
  const int lane = t & 63, w = t >> 6;
  int cap = *capp; if (cap > CAPC) cap = CAPC;
  if (e == 0 && t == 0) *nfb = 0;
  __shared__ int wtot[16];
  int base = 0;
  for (int i0 = 0; i0 < NASSIGN; i0 += 1024) {
    int i = i0 + t;
    int r = routes[i];
    bool mine = (r == e);
    unsigned long long mask = __ballot(mine);
    int pre = __popcll(mask & ((1ull << lane) - 1ull));
    if (lane == 0) wtot[w] = __popcll(mask);
    __syncthreads();
    int tot = 0;
#pragma unroll
    for (int j = 0; j < 16; ++j) { int c = wtot[j]; if (j < w) pre += c; tot += c; }
    if (e == 0 && (unsigned)r >= NEXP) slot[i] = -1;  // defensive (never triggers)
    if (mine) {
      int pos = base + pre;
      if (pos < cap) { gidx[e * CAPC + pos] = i >> 1; slot[i] = e * CAPC + pos; }
      else slot[i] = -1;
    }
    base += tot;
    __syncthreads();
  }
  if (t == 0) counts[e] = base < cap ? base : cap;
}

// ---------------- merged: fb_list (blocks 0..31) + gather_xg (blocks 32..) ----
__global__ void fblist_gxg_kernel(const int* __restrict__ slot, int* __restrict__ fbidx,
                                  int* __restrict__ nfb,
                                  const float* __restrict__ x, const int* __restrict__ gidx,
                                  const int* __restrict__ counts, ushort_t* __restrict__ xg) {
  int b = blockIdx.x, t = threadIdx.x;
  if (b < 32) {                          // fallback token list (used==0)
    int tok = b * 256 + t;
    int u = (slot[2 * tok] >= 0) + (slot[2 * tok + 1] >= 0);
    if (u == 0) { int p = atomicAdd(nfb, 1); fbidx[p] = tok; }
    return;
  }
  int row = b - 32;                      // gather accepted rows -> xg
  int e = row / CAPC, p = row % CAPC;
  int d = t * 4;
  ushort4 o = {0, 0, 0, 0};
  if (p < counts[e]) {
    int tok = gidx[row];
    float4 v = *(const float4*)(x + (size_t)tok * DM + d);
    o.x = f2b(v.x); o.y = f2b(v.y); o.z = f2b(v.z); o.w = f2b(v.w);
  }
  *(ushort4*)(xg + (size_t)row * DM + d) = o;
}

// -------- merged: gather xf rows (blocks 0..8191) + W2/Wf2 cvt (8192..) ------
// cvt blocks: 256 thr x 4 float4 = 1024 float4 per block.  W2: 2048 blocks,
// Wf2: 256.  These ride in the same latency-dominated pre-layer-1 window.
__global__ void gather_xf_kernel(const float* __restrict__ x, const int* __restrict__ fbidx,
                                 const int* __restrict__ nfbp, ushort_t* __restrict__ xf,
                                 const float* __restrict__ W2, const float* __restrict__ Wf2,
                                 ushort_t* __restrict__ o2, ushort_t* __restrict__ of2) {
  int row = blockIdx.x, t = threadIdx.x;
  if (row >= BTOK) {                     // W2 / Wf2 f32 -> bf16
    int c = row - BTOK;
    const float* s; ushort_t* d; int idx;
    if (c < 2048) { s = W2;  d = o2;  idx = c; }
    else          { s = Wf2; d = of2; idx = c - 2048; }
    const float4* sp = (const float4*)s + (size_t)idx * 1024;
    ushort4*      dp = (ushort4*)d      + (size_t)idx * 1024;
#pragma unroll
    for (int q = 0; q < 4; ++q) {
      float4 v = sp[q * 256 + t];
      ushort4 o; o.x = f2b(v.x); o.y = f2b(v.y); o.z = f2b(v.z); o.w = f2b(v.w);
      dp[q * 256 + t] = o;
    }
    return;
  }
  int n = *nfbp;
  int nr = (n + 127) & ~127;
  if (row >= nr) return;
  int d = t * 4;
  ushort4 o = {0, 0, 0, 0};
  if (row < n) {
    int tok = fbidx[row];
    float4 v = *(const float4*)(x + (size_t)tok * DM + d);
    o.x = f2b(v.x); o.y = f2b(v.y); o.z = f2b(v.z); o.w = f2b(v.w);
  }
  *(ushort4*)(xf + (size_t)row * DM + d) = o;
}

// ---------------- fused layer GEMM: expert part + fallback part ----------------
// C[m,n] = A[m,k]*W[n,k] + bias[n].  r15 exact (session best, 43.6us/layer):
// 256x128 tile, BK=32, 8 waves (4Mx2N), per-wave 64x64 (acc in AGPRs, VGPR 64
// + 64 AGPR = 128 unified -> 4 waves/SIMD, 2 blocks/CU).  Simple 2-phase dbuf,
// ONE __syncthreads per K-step.  This structure's cycle budget is a balanced
// LDS-read/MFMA/latency split -- all rebalancing attempts (8-phase r13/r14,
// counted-vmcnt r2/r5/r10, occupancy forcing r11, fusions r16/r17) regressed.
// XCD expert affinity kept.  LDS XOR swizzle kept.  LDS-repack epilogue kept.
template <int RELU, int FBSCAT>
__global__ __launch_bounds__(512, 4) void layer_kernel(
    const ushort_t* __restrict__ Ae, const ushort_t* __restrict__ We,
    const float* __restrict__ be, ushort_t* __restrict__ Ce,
    const ushort_t* __restrict__ Af, const ushort_t* __restrict__ Wf,
    const float* __restrict__ bfp, ushort_t* __restrict__ Cf,
    float* __restrict__ outF, const int* __restrict__ scat,
    const int* __restrict__ nfbp) {
  const int b = blockIdx.x;
  const int xcd = b & 7, s = b >> 3;
  const ushort_t* A; const ushort_t* W; const float* bias; ushort_t* C;
  int mgrp, ntile; bool isfb;
  if (s < SLOTS_E) {
    const int e = xcd;                       // expert = XCD (L2 affinity)
    mgrp = e * 5 + (s >> 3); ntile = s & 7;  // N-fastest
    A = Ae; W = We + (size_t)e * DM * DM; bias = be + e * DM; C = Ce; isfb = false;
  } else {
    int fl = (s - SLOTS_E) * 8 + xcd;        // 0..255 spread over XCDs
    mgrp = fl >> 3; ntile = fl & 7;
    if (mgrp * 256 >= *nfbp) return;
    A = Af; W = Wf; bias = bfp; C = Cf; isfb = true;
  }
  const int tid = threadIdx.x, lane = tid & 63, w = tid >> 6;  // w 0..7
  const int wr = w >> 1, wc = w & 1;        // 4Mx2N wave grid
  __shared__ ushort_t smem[24576];          // 48KB: A dbuf 2x16KB, B dbuf 2x8KB
  const size_t Abase = (size_t)mgrp * 256 * DM;
  const size_t Wbase = (size_t)ntile * 128 * DM;
  f32x4 acc[4][4] = {};

  // staging: A = 16 segs of 16 rows x 32k (1KB), wave w stages segs 2w,2w+1;
  // B = 8 segs, wave w stages seg w.  3 global_load_lds per thread per K-step.
  const int sub  = lane >> 2;                     // row within 16-row seg
  const int slt  = lane & 3;                      // 16B k-slot
  const int gcol = (slt ^ ((sub >> 1) & 3)) * 8;  // inverse-swizzled source k-off
  const int ra0 = (w * 2)     * 16 + sub;
  const int ra1 = (w * 2 + 1) * 16 + sub;
  const int rbw = w * 16 + sub;

  // LDS elems: A buf0 @0, A buf1 @8192, B buf0 @16384, B buf1 @20480
#define STAGE(T, BUF) do { int kt_ = (T) * 32;                                        \
    GLOAD_LDS(A + Abase + (size_t)ra0 * DM + kt_ + gcol, smem + (BUF)*8192 + (w*2)  *512); \
    GLOAD_LDS(A + Abase + (size_t)ra1 * DM + kt_ + gcol, smem + (BUF)*8192 + (w*2+1)*512); \
    GLOAD_LDS(W + Wbase + (size_t)rbw * DM + kt_ + gcol, smem + 16384 + (BUF)*4096 + w*512); \
  } while (0)

  const int fr    = lane & 15, g = lane >> 4;
  const int rslot = (g ^ ((fr >> 1) & 3)) * 8;    // swizzled read k-off

  STAGE(0, 0);
  for (int t = 0; t < 32; ++t) {
    __syncthreads();                    // vmcnt(0) drain: tile t landed; and
                                        // buf[p^1]'s readers (iter t-1) passed
    if (t + 1 < 32) STAGE(t + 1, (t + 1) & 1);
    const ushort_t* bA = smem + (t & 1) * 8192;
    const ushort_t* bB = smem + 16384 + (t & 1) * 4096;
    bf16x8 av[4], bv[4];
#pragma unroll
    for (int m = 0; m < 4; ++m)
      av[m] = *(const bf16x8*)&bA[(wr * 64 + m * 16 + fr) * 32 + rslot];
#pragma unroll
    for (int n = 0; n < 4; ++n)
      bv[n] = *(const bf16x8*)&bB[(wc * 64 + n * 16 + fr) * 32 + rslot];
#pragma unroll
    for (int m = 0; m < 4; ++m)
#pragma unroll
      for (int n = 0; n < 4; ++n)
        acc[m][n] = __builtin_amdgcn_mfma_f32_16x16x32_bf16(av[m], bv[n], acc[m][n], 0, 0, 0);
  }
#undef STAGE

  // epilogue.  C/D layout col=lane&15, row=(lane>>4)*4+reg  [m89-verified]
  if (FBSCAT && isfb) {                 // fb layer-2: f32 scatter (small)
    int nfbv = *nfbp;
#pragma unroll
    for (int n = 0; n < 4; ++n) {
      int col = ntile * 128 + wc * 64 + n * 16 + fr;
      float bb = bias[col];
#pragma unroll
      for (int m = 0; m < 4; ++m) {
        int row0 = mgrp * 256 + wr * 64 + m * 16 + g * 4;
#pragma unroll
        for (int r = 0; r < 4; ++r) {
          int row = row0 + r;
          if (row < nfbv) outF[(size_t)scat[row] * DM + col] = acc[m][n][r] + bb;
        }
      }
    }
  } else {                              // bf16 C: LDS repack in 2 halves
    ushort_t* Cb = C + (size_t)mgrp * 256 * DM + ntile * 128;
#pragma unroll
    for (int h = 0; h < 2; ++h) {
      __syncthreads();                  // staging reads (h=0) / prior copy (h=1) done
      if ((wr >> 1) == h) {             // waves wr={2h,2h+1} own these 128 rows
#pragma unroll
        for (int n = 0; n < 4; ++n) {
          int col = wc * 64 + n * 16 + fr;
          float bb = bias[ntile * 128 + col];
#pragma unroll
          for (int m = 0; m < 4; ++m) {
            int lrow0 = (wr & 1) * 64 + m * 16 + g * 4;
#pragma unroll
            for (int r = 0; r < 4; ++r) {
              float v = acc[m][n][r] + bb;
              if (RELU) v = v > 0.0f ? v : 0.0f;
              smem[(lrow0 + r) * 128 + col] = f2b(v);
            }
          }
        }
      }
      __syncthreads();
      // copy 128x128 bf16 half-tile: 2048 chunks of 16B, 512 thr x 4
#pragma unroll
      for (int q = 0; q < 4; ++q) {
        int chunk = q * 512 + tid;      // 0..2047
        int row = chunk >> 4, co = (chunk & 15) * 8;
        bf16x8 v = *(const bf16x8*)&smem[row * 128 + co];
        *(bf16x8*)(Cb + (size_t)(h * 128 + row) * DM + co) = v;
      }
    }
  }
}

// ---------------- combine accepted expert outputs per token ----------------
__global__ void combine_kernel(const ushort_t* __restrict__ Y, const int* __restrict__ slot,
                               float* __restrict__ out) {
  int t = blockIdx.x;
  int s0 = slot[2 * t], s1 = slot[2 * t + 1];
  int u = (s0 >= 0) + (s1 >= 0);
  if (u == 0) return;  // fallback GEMM scatter writes these rows
  int d = threadIdx.x * 4;
  float a0 = 0, a1 = 0, a2 = 0, a3 = 0;
  if (s0 >= 0) {
    ushort4 q = *(const ushort4*)(Y + (size_t)s0 * DM + d);
    a0 += b2f(q.x); a1 += b2f(q.y); a2 += b2f(q.z); a3 += b2f(q.w);
  }
  if (s1 >= 0) {
    ushort4 q = *(const ushort4*)(Y + (size_t)s1 * DM + d);
    a0 += b2f(q.x); a1 += b2f(q.y); a2 += b2f(q.z); a3 += b2f(q.w);
  }
  float inv = 1.0f / (float)u;
  float4 o = make_float4(a0 * inv, a1 * inv, a2 * inv, a3 * inv);
  *(float4*)(out + (size_t)t * DM + d) = o;
}

// ---------------- launch ----------------
extern "C" void kernel_launch(void* const* d_in, const int* in_sizes, int n_in,
                              void* d_out, int out_size, void* d_ws, size_t ws_size,
                              hipStream_t stream) {
  const float* x   = (const float*)d_in[0];
  const float* W1  = (const float*)d_in[1];
  const float* b1  = (const float*)d_in[2];
  const float* W2  = (const float*)d_in[3];
  const float* b2  = (const float*)d_in[4];
  const float* Wf1 = (const float*)d_in[5];
  const float* bf1 = (const float*)d_in[6];
  const float* Wf2 = (const float*)d_in[7];
  const float* bf2 = (const float*)d_in[8];
  const int* routes = (const int*)d_in[9];
  const int* capp   = (const int*)d_in[10];
  float* out = (float*)d_out;

  char* ws = (char*)d_ws;
  size_t off = 0;
  auto alloc = [&](size_t bytes) -> void* {
    void* p = ws + off; off += (bytes + 255) & ~255ull; return p;
  };
  ushort_t* W1b  = (ushort_t*)alloc((size_t)NEXP * DM * DM * 2);
  ushort_t* W2b  = (ushort_t*)alloc((size_t)NEXP * DM * DM * 2);
  ushort_t* Wf1b = (ushort_t*)alloc((size_t)DM * DM * 2);
  ushort_t* Wf2b = (ushort_t*)alloc((size_t)DM * DM * 2);
  ushort_t* xg   = (ushort_t*)alloc((size_t)MROWS * DM * 2);
  ushort_t* H    = (ushort_t*)alloc((size_t)MROWS * DM * 2);
  ushort_t* Y    = (ushort_t*)alloc((size_t)MROWS * DM * 2);
  ushort_t* xf   = (ushort_t*)alloc((size_t)BTOK * DM * 2);
  ushort_t* Hf   = (ushort_t*)alloc((size_t)BTOK * DM * 2);
  int* gidx   = (int*)alloc(MROWS * 4);
  int* slot   = (int*)alloc(NASSIGN * 4);
  int* counts = (int*)alloc(NEXP * 4);
  int* fbidx  = (int*)alloc(BTOK * 4);
  int* nfb    = (int*)alloc(4);

  route_cvt_kernel<<<8 + 2304, 1024, 0, stream>>>(routes, capp, gidx, slot, counts, nfb,
                                                  W1, Wf1, W1b, Wf1b);
  fblist_gxg_kernel<<<32 + MROWS, 256, 0, stream>>>(slot, fbidx, nfb, x, gidx, counts, xg);
  gather_xf_kernel<<<BTOK + 2304, 256, 0, stream>>>(x, fbidx, nfb, xf,
                                                    W2, Wf2, W2b, Wf2b);
  layer_kernel<1, 0><<<GRID_L, 512, 0, stream>>>(xg, W1b, b1, H, xf, Wf1b, bf1, Hf,
                                                 nullptr, nullptr, nfb);
  layer_kernel<0, 1><<<GRID_L, 512, 0, stream>>>(H, W2b, b2, Y, Hf, Wf2b, bf2, nullptr,
                                                 out, fbidx, nfb);
  combine_kernel<<<BTOK, 256, 0, stream>>>(Y, slot, out);
}

// Round 20
// 128.510 us; speedup vs baseline: 1.0389x; 1.0389x over previous
//
#include <hip/hip_runtime.h>

// ---------------- problem constants ----------------
#define DM    1024          // d_model
#define NEXP  8             // experts
#define BTOK  8192          // tokens
#define KTOP  2             // routes per token
#define NASSIGN (BTOK*KTOP) // 16384
#define CAPC  1280          // capacity (5 * 256 -> tile-aligned)
#define MROWS (NEXP*CAPC)   // 10240 expert rows

// GEMM geometry: 256M x 128N tile, BK=32, 8 waves (4Mx2N), per-wave 64x64
#define NTILES   (DM/128)      // 8
#define SLOTS_E  (5*NTILES)    // 40 expert slots per XCD (5 Mtiles x 8 N)
#define SLOTS_F  (32*NTILES/8) // 32 fb slots per XCD
#define SLOTS    (SLOTS_E+SLOTS_F)    // 72
#define GRID_L   (8*SLOTS)            // 576

typedef unsigned short ushort_t;
typedef __attribute__((ext_vector_type(8))) __bf16 bf16x8;
typedef __attribute__((ext_vector_type(4))) float  f32x4;

__device__ __forceinline__ ushort_t f2b(float f) {  // f32 -> bf16 RNE
  union { float f; unsigned u; } a; a.f = f;
  unsigned u = a.u;
  return (ushort_t)((u + 0x7FFFu + ((u >> 16) & 1u)) >> 16);
}
__device__ __forceinline__ float b2f(ushort_t h) {
  union { unsigned u; float f; } a; a.u = ((unsigned)h) << 16;
  return a.f;
}

#define GLOAD_LDS(g, l) __builtin_amdgcn_global_load_lds( \
    (const __attribute__((address_space(1))) void*)(g),   \
    (__attribute__((address_space(3))) void*)(l), 16, 0, 0)

// ---------------- merged: routing (blocks 0..7) + weight cvt (blocks 8..) ----
__global__ void route_cvt_kernel(const int* __restrict__ routes, const int* __restrict__ capp,
                                 int* __restrict__ gidx, int* __restrict__ slot,
                                 int* __restrict__ counts, int* __restrict__ nfb,
                                 const float* __restrict__ W1, const float* __restrict__ W2,
                                 const float* __restrict__ Wf1, const float* __restrict__ Wf2,
                                 ushort_t* __restrict__ o1, ushort_t* __restrict__ o2,
                                 ushort_t* __restrict__ of1, ushort_t* __restrict__ of2) {
  const int b = blockIdx.x, t = threadIdx.x;
  if (b >= 8) {                          // weight f32 -> bf16
    const float* s; ushort_t* d; int idx;
    int c = b - 8;
    if (c < 2048)      { s = W1;  d = o1;  idx = c; }
    else if (c < 4096) { s = W2;  d = o2;  idx = c - 2048; }
    else if (c < 4352) { s = Wf1; d = of1; idx = c - 4096; }
    else               { s = Wf2; d = of2; idx = c - 4352; }
    int i = idx * 1024 + t;
    float4 v = ((const float4*)s)[i];
    ushort4 o; o.x = f2b(v.x); o.y = f2b(v.y); o.z = f2b(v.z); o.w = f2b(v.w);
    ((ushort4*)d)[i] = o;
    return;
  }
  // ---- routing: exact sequential capacity semantics (block e = expert) ----
  const int e = b;
  const int lane = t & 63, w = t >> 6;
  int cap = *capp; if (cap > CAPC) cap = CAPC;
  if (e == 0 && t == 0) *nfb = 0;
  __shared__ int wtot[16];
  int base = 0;
  for (int i0 = 0; i0 < NASSIGN; i0 += 1024) {
    int i = i0 + t;
    int r = routes[i];
    bool mine = (r == e);
    unsigned long long mask = __ballot(mine);
    int pre = __popcll(mask & ((1ull << lane) - 1ull));
    if (lane == 0) wtot[w] = __popcll(mask);
    __syncthreads();
    int tot = 0;
#pragma unroll
    for (int j = 0; j < 16; ++j) { int c = wtot[j]; if (j < w) pre += c; tot += c; }
    if (e == 0 && (unsigned)r >= NEXP) slot[i] = -1;  // defensive (never triggers)
    if (mine) {
      int pos = base + pre;
      if (pos < cap) { gidx[e * CAPC + pos] = i >> 1; slot[i] = e * CAPC + pos; }
      else slot[i] = -1;
    }
    base += tot;
    __syncthreads();
  }
  if (t == 0) counts[e] = base < cap ? base : cap;
}

// ---------------- merged: fb_list (blocks 0..31) + gather_xg (blocks 32..) ----
__global__ void fblist_gxg_kernel(const int* __restrict__ slot, int* __restrict__ fbidx,
                                  int* __restrict__ nfb,
                                  const float* __restrict__ x, const int* __restrict__ gidx,
                                  const int* __restrict__ counts, ushort_t* __restrict__ xg) {
  int b = blockIdx.x, t = threadIdx.x;
  if (b < 32) {                          // fallback token list (used==0)
    int tok = b * 256 + t;
    int u = (slot[2 * tok] >= 0) + (slot[2 * tok + 1] >= 0);
    if (u == 0) { int p = atomicAdd(nfb, 1); fbidx[p] = tok; }
    return;
  }
  int row = b - 32;                      // gather accepted rows -> xg
  int e = row / CAPC, p = row % CAPC;
  int d = t * 4;
  ushort4 o = {0, 0, 0, 0};
  if (p < counts[e]) {
    int tok = gidx[row];
    float4 v = *(const float4*)(x + (size_t)tok * DM + d);
    o.x = f2b(v.x); o.y = f2b(v.y); o.z = f2b(v.z); o.w = f2b(v.w);
  }
  *(ushort4*)(xg + (size_t)row * DM + d) = o;
}

// ---------------- gather fallback token rows -> xf (bf16), zero pad to 128 ----
__global__ void gather_xf_kernel(const float* __restrict__ x, const int* __restrict__ fbidx,
                                 const int* __restrict__ nfbp, ushort_t* __restrict__ xf) {
  int row = blockIdx.x;
  int n = *nfbp;
  int nr = (n + 127) & ~127;
  if (row >= nr) return;
  int d = threadIdx.x * 4;
  ushort4 o = {0, 0, 0, 0};
  if (row < n) {
    int tok = fbidx[row];
    float4 v = *(const float4*)(x + (size_t)tok * DM + d);
    o.x = f2b(v.x); o.y = f2b(v.y); o.z = f2b(v.z); o.w = f2b(v.w);
  }
  *(ushort4*)(xf + (size_t)row * DM + d) = o;
}

// ---------------- fused layer GEMM: expert part + fallback part ----------------
// C[m,n] = A[m,k]*W[n,k] + bias[n].  r15/r18 exact (session best, 43.6us/layer,
// ~660 TF): 256x128 tile, BK=32, 8 waves (4Mx2N), per-wave 64x64 (acc in
// AGPRs; 64 VGPR + 64 AGPR = 128 unified -> 4 waves/SIMD, 2 blocks/CU,
// 16 waves/CU).  Simple 2-phase dbuf, ONE __syncthreads per K-step.
// Exhaustively measured alternatives all regressed: 8-phase (r13/r14),
// counted-vmcnt rings (r2/r5/r10), occupancy forcing (r11), gather/combine
// fusions (r16/r17/r19).  XCD expert affinity + LDS XOR swizzle +
// LDS-repack coalesced epilogue are the load-bearing techniques.
template <int RELU, int FBSCAT>
__global__ __launch_bounds__(512, 4) void layer_kernel(
    const ushort_t* __restrict__ Ae, const ushort_t* __restrict__ We,
    const float* __restrict__ be, ushort_t* __restrict__ Ce,
    const ushort_t* __restrict__ Af, const ushort_t* __restrict__ Wf,
    const float* __restrict__ bfp, ushort_t* __restrict__ Cf,
    float* __restrict__ outF, const int* __restrict__ scat,
    const int* __restrict__ nfbp) {
  const int b = blockIdx.x;
  const int xcd = b & 7, s = b >> 3;
  const ushort_t* A; const ushort_t* W; const float* bias; ushort_t* C;
  int mgrp, ntile; bool isfb;
  if (s < SLOTS_E) {
    const int e = xcd;                       // expert = XCD (L2 affinity)
    mgrp = e * 5 + (s >> 3); ntile = s & 7;  // N-fastest
    A = Ae; W = We + (size_t)e * DM * DM; bias = be + e * DM; C = Ce; isfb = false;
  } else {
    int fl = (s - SLOTS_E) * 8 + xcd;        // 0..255 spread over XCDs
    mgrp = fl >> 3; ntile = fl & 7;
    if (mgrp * 256 >= *nfbp) return;
    A = Af; W = Wf; bias = bfp; C = Cf; isfb = true;
  }
  const int tid = threadIdx.x, lane = tid & 63, w = tid >> 6;  // w 0..7
  const int wr = w >> 1, wc = w & 1;        // 4Mx2N wave grid
  __shared__ ushort_t smem[24576];          // 48KB: A dbuf 2x16KB, B dbuf 2x8KB
  const size_t Abase = (size_t)mgrp * 256 * DM;
  const size_t Wbase = (size_t)ntile * 128 * DM;
  f32x4 acc[4][4] = {};

  // staging: A = 16 segs of 16 rows x 32k (1KB), wave w stages segs 2w,2w+1;
  // B = 8 segs, wave w stages seg w.  3 global_load_lds per thread per K-step.
  const int sub  = lane >> 2;                     // row within 16-row seg
  const int slt  = lane & 3;                      // 16B k-slot
  const int gcol = (slt ^ ((sub >> 1) & 3)) * 8;  // inverse-swizzled source k-off
  const int ra0 = (w * 2)     * 16 + sub;
  const int ra1 = (w * 2 + 1) * 16 + sub;
  const int rbw = w * 16 + sub;

  // LDS elems: A buf0 @0, A buf1 @8192, B buf0 @16384, B buf1 @20480
#define STAGE(T, BUF) do { int kt_ = (T) * 32;                                        \
    GLOAD_LDS(A + Abase + (size_t)ra0 * DM + kt_ + gcol, smem + (BUF)*8192 + (w*2)  *512); \
    GLOAD_LDS(A + Abase + (size_t)ra1 * DM + kt_ + gcol, smem + (BUF)*8192 + (w*2+1)*512); \
    GLOAD_LDS(W + Wbase + (size_t)rbw * DM + kt_ + gcol, smem + 16384 + (BUF)*4096 + w*512); \
  } while (0)

  const int fr    = lane & 15, g = lane >> 4;
  const int rslot = (g ^ ((fr >> 1) & 3)) * 8;    // swizzled read k-off

  STAGE(0, 0);
  for (int t = 0; t < 32; ++t) {
    __syncthreads();                    // vmcnt(0) drain: tile t landed; and
                                        // buf[p^1]'s readers (iter t-1) passed
    if (t + 1 < 32) STAGE(t + 1, (t + 1) & 1);
    const ushort_t* bA = smem + (t & 1) * 8192;
    const ushort_t* bB = smem + 16384 + (t & 1) * 4096;
    bf16x8 av[4], bv[4];
#pragma unroll
    for (int m = 0; m < 4; ++m)
      av[m] = *(const bf16x8*)&bA[(wr * 64 + m * 16 + fr) * 32 + rslot];
#pragma unroll
    for (int n = 0; n < 4; ++n)
      bv[n] = *(const bf16x8*)&bB[(wc * 64 + n * 16 + fr) * 32 + rslot];
#pragma unroll
    for (int m = 0; m < 4; ++m)
#pragma unroll
      for (int n = 0; n < 4; ++n)
        acc[m][n] = __builtin_amdgcn_mfma_f32_16x16x32_bf16(av[m], bv[n], acc[m][n], 0, 0, 0);
  }
#undef STAGE

  // epilogue.  C/D layout col=lane&15, row=(lane>>4)*4+reg  [m89-verified]
  if (FBSCAT && isfb) {                 // fb layer-2: f32 scatter (small)
    int nfbv = *nfbp;
#pragma unroll
    for (int n = 0; n < 4; ++n) {
      int col = ntile * 128 + wc * 64 + n * 16 + fr;
      float bb = bias[col];
#pragma unroll
      for (int m = 0; m < 4; ++m) {
        int row0 = mgrp * 256 + wr * 64 + m * 16 + g * 4;
#pragma unroll
        for (int r = 0; r < 4; ++r) {
          int row = row0 + r;
          if (row < nfbv) outF[(size_t)scat[row] * DM + col] = acc[m][n][r] + bb;
        }
      }
    }
  } else {                              // bf16 C: LDS repack in 2 halves
    ushort_t* Cb = C + (size_t)mgrp * 256 * DM + ntile * 128;
#pragma unroll
    for (int h = 0; h < 2; ++h) {
      __syncthreads();                  // staging reads (h=0) / prior copy (h=1) done
      if ((wr >> 1) == h) {             // waves wr={2h,2h+1} own these 128 rows
#pragma unroll
        for (int n = 0; n < 4; ++n) {
          int col = wc * 64 + n * 16 + fr;
          float bb = bias[ntile * 128 + col];
#pragma unroll
          for (int m = 0; m < 4; ++m) {
            int lrow0 = (wr & 1) * 64 + m * 16 + g * 4;
#pragma unroll
            for (int r = 0; r < 4; ++r) {
              float v = acc[m][n][r] + bb;
              if (RELU) v = v > 0.0f ? v : 0.0f;
              smem[(lrow0 + r) * 128 + col] = f2b(v);
            }
          }
        }
      }
      __syncthreads();
      // copy 128x128 bf16 half-tile: 2048 chunks of 16B, 512 thr x 4
#pragma unroll
      for (int q = 0; q < 4; ++q) {
        int chunk = q * 512 + tid;      // 0..2047
        int row = chunk >> 4, co = (chunk & 15) * 8;
        bf16x8 v = *(const bf16x8*)&smem[row * 128 + co];
        *(bf16x8*)(Cb + (size_t)(h * 128 + row) * DM + co) = v;
      }
    }
  }
}

// ---------------- combine accepted expert outputs per token ----------------
__global__ void combine_kernel(const ushort_t* __restrict__ Y, const int* __restrict__ slot,
                               float* __restrict__ out) {
  int t = blockIdx.x;
  int s0 = slot[2 * t], s1 = slot[2 * t + 1];
  int u = (s0 >= 0) + (s1 >= 0);
  if (u == 0) return;  // fallback GEMM scatter writes these rows
  int d = threadIdx.x * 4;
  float a0 = 0, a1 = 0, a2 = 0, a3 = 0;
  if (s0 >= 0) {
    ushort4 q = *(const ushort4*)(Y + (size_t)s0 * DM + d);
    a0 += b2f(q.x); a1 += b2f(q.y); a2 += b2f(q.z); a3 += b2f(q.w);
  }
  if (s1 >= 0) {
    ushort4 q = *(const ushort4*)(Y + (size_t)s1 * DM + d);
    a0 += b2f(q.x); a1 += b2f(q.y); a2 += b2f(q.z); a3 += b2f(q.w);
  }
  float inv = 1.0f / (float)u;
  float4 o = make_float4(a0 * inv, a1 * inv, a2 * inv, a3 * inv);
  *(float4*)(out + (size_t)t * DM + d) = o;
}

// ---------------- launch ----------------
extern "C" void kernel_launch(void* const* d_in, const int* in_sizes, int n_in,
                              void* d_out, int out_size, void* d_ws, size_t ws_size,
                              hipStream_t stream) {
  const float* x   = (const float*)d_in[0];
  const float* W1  = (const float*)d_in[1];
  const float* b1  = (const float*)d_in[2];
  const float* W2  = (const float*)d_in[3];
  const float* b2  = (const float*)d_in[4];
  const float* Wf1 = (const float*)d_in[5];
  const float* bf1 = (const float*)d_in[6];
  const float* Wf2 = (const float*)d_in[7];
  const float* bf2 = (const float*)d_in[8];
  const int* routes = (const int*)d_in[9];
  const int* capp   = (const int*)d_in[10];
  float* out = (float*)d_out;

  char* ws = (char*)d_ws;
  size_t off = 0;
  auto alloc = [&](size_t bytes) -> void* {
    void* p = ws + off; off += (bytes + 255) & ~255ull; return p;
  };
  ushort_t* W1b  = (ushort_t*)alloc((size_t)NEXP * DM * DM * 2);
  ushort_t* W2b  = (ushort_t*)alloc((size_t)NEXP * DM * DM * 2);
  ushort_t* Wf1b = (ushort_t*)alloc((size_t)DM * DM * 2);
  ushort_t* Wf2b = (ushort_t*)alloc((size_t)DM * DM * 2);
  ushort_t* xg   = (ushort_t*)alloc((size_t)MROWS * DM * 2);
  ushort_t* H    = (ushort_t*)alloc((size_t)MROWS * DM * 2);
  ushort_t* Y    = (ushort_t*)alloc((size_t)MROWS * DM * 2);
  ushort_t* xf   = (ushort_t*)alloc((size_t)BTOK * DM * 2);
  ushort_t* Hf   = (ushort_t*)alloc((size_t)BTOK * DM * 2);
  int* gidx   = (int*)alloc(MROWS * 4);
  int* slot   = (int*)alloc(NASSIGN * 4);
  int* counts = (int*)alloc(NEXP * 4);
  int* fbidx  = (int*)alloc(BTOK * 4);
  int* nfb    = (int*)alloc(4);

  route_cvt_kernel<<<8 + 4608, 1024, 0, stream>>>(routes, capp, gidx, slot, counts, nfb,
                                                  W1, W2, Wf1, Wf2, W1b, W2b, Wf1b, Wf2b);
  fblist_gxg_kernel<<<32 + MROWS, 256, 0, stream>>>(slot, fbidx, nfb, x, gidx, counts, xg);
  gather_xf_kernel<<<BTOK, 256, 0, stream>>>(x, fbidx, nfb, xf);
  layer_kernel<1, 0><<<GRID_L, 512, 0, stream>>>(xg, W1b, b1, H, xf, Wf1b, bf1, Hf,
                                                 nullptr, nullptr, nfb);
  layer_kernel<0, 1><<<GRID_L, 512, 0, stream>>>(H, W2b, b2, Y, Hf, Wf2b, bf2, nullptr,
                                                 out, fbidx, nfb);
  combine_kernel<<<BTOK, 256, 0, stream>>>(Y, slot, out);
}